// Round 2
// baseline (496.942 us; speedup 1.0000x reference)
//
#include <hip/hip_runtime.h>
#include <hip/hip_bf16.h>
#include <stdint.h>

#define DEVI __device__ __forceinline__

typedef short s8v __attribute__((ext_vector_type(8)));
typedef float f4v __attribute__((ext_vector_type(4)));

DEVI short f2bf(float f) {
  unsigned u = __builtin_bit_cast(unsigned, f);
  u += 0x7FFFu + ((u >> 16) & 1u);
  return (short)(u >> 16);
}

DEVI void gload16(const void* g, void* l) {
  __builtin_amdgcn_global_load_lds((const __attribute__((address_space(1))) unsigned*)g,
                                   (__attribute__((address_space(3))) unsigned*)l,
                                   16, 0, 0);
}

// ---------------- prep kernels ----------------

// state [B,H,L,D] f32 -> xbf [B,L,E] bf16
__global__ __launch_bounds__(256) void k_tr_state(const float* __restrict__ st,
                                                  short* __restrict__ xbf) {
  int idx = blockIdx.x * 256 + threadIdx.x;      // 8*12*2048*8 threads
  int dc = idx & 7;
  int l  = (idx >> 3) & 2047;
  int hb = idx >> 14;                            // b*12 + h
  int h = hb % 12, b = hb / 12;
  const float* s = st + ((size_t)hb * 2048 + l) * 64 + dc * 8;
  f4v a = *(const f4v*)s;
  f4v c = *(const f4v*)(s + 4);
  short o[8];
#pragma unroll
  for (int j = 0; j < 4; ++j) { o[j] = f2bf(a[j]); o[4 + j] = f2bf(c[j]); }
  *(s8v*)(xbf + ((size_t)(b * 2048 + l)) * 768 + h * 64 + dc * 8) = *(s8v*)o;
}

// f32 -> bf16 elementwise (weights)
__global__ __launch_bounds__(256) void k_castw(const float* __restrict__ src,
                                               short* __restrict__ dst) {
  int idx = blockIdx.x * 256 + threadIdx.x;
  const float* s = src + (size_t)idx * 8;
  f4v a = *(const f4v*)s;
  f4v c = *(const f4v*)(s + 4);
  short o[8];
#pragma unroll
  for (int j = 0; j < 4; ++j) { o[j] = f2bf(a[j]); o[4 + j] = f2bf(c[j]); }
  *(s8v*)(dst + (size_t)idx * 8) = *(s8v*)o;
}

// Wq [3][768][768] f32 -> Wqt [768][2304] bf16 : Wqt[o][kw*768+i] = Wq[kw][i][o]
__global__ __launch_bounds__(256) void k_tr_wq(const float* __restrict__ wq,
                                               short* __restrict__ wqt) {
  __shared__ float tile[32][33];
  const int kw = blockIdx.z;
  const int i0 = blockIdx.y * 32, o0 = blockIdx.x * 32;
  const int tx = threadIdx.x & 31, ty = threadIdx.x >> 5;
#pragma unroll
  for (int rr = 0; rr < 32; rr += 8)
    tile[ty + rr][tx] = wq[((size_t)kw * 768 + i0 + ty + rr) * 768 + o0 + tx];
  __syncthreads();
#pragma unroll
  for (int rr = 0; rr < 32; rr += 8)
    wqt[(size_t)(o0 + ty + rr) * 2304 + kw * 768 + i0 + tx] = f2bf(tile[tx][ty + rr]);
}

// v [B,L,768] bf16 -> vt [96*64][2048] bf16 : vt[bh*64+d][l] = v[b][l][h*64+d]
__global__ __launch_bounds__(256) void k_tr_v(const short* __restrict__ v,
                                              short* __restrict__ vt) {
  __shared__ short tile[32][33];
  const int bh = blockIdx.z;
  const int l0 = blockIdx.x * 32, d0 = blockIdx.y * 32;
  const int b = bh / 12, h = bh % 12;
  const int tx = threadIdx.x & 31, ty = threadIdx.x >> 5;
#pragma unroll
  for (int rr = 0; rr < 32; rr += 8)
    tile[ty + rr][tx] = v[((size_t)(b * 2048 + l0 + ty + rr)) * 768 + h * 64 + d0 + tx];
  __syncthreads();
#pragma unroll
  for (int rr = 0; rr < 32; rr += 8)
    vt[((size_t)(bh * 64 + d0 + ty + rr)) * 2048 + l0 + tx] = tile[tx][ty + rr];
}

// ---------------- GEMM:  C = act(A @ Bt^T + bias) ----------------
// A [M,K] bf16 row-major (AMODE 1: conv-gathered view of y), Bt [N,K] bf16.
// EPI: 0 relu->bf16, 1 bf16, 2 final fp32 + strided residual.
template <int AMODE, int EPI>
__global__ __launch_bounds__(256, 2)
void k_gemm(const short* __restrict__ A, const short* __restrict__ Bt,
            const float* __restrict__ bias, short* __restrict__ Cbf,
            float* __restrict__ Cf, const float* __restrict__ st,
            const short* __restrict__ zp, int M, int N, int K) {
  __shared__ __align__(16) short As[128 * 32];
  __shared__ __align__(16) short Bs[128 * 32];
  const int tid = threadIdx.x;
  const int w = tid >> 6, l = tid & 63;
  const int g = l >> 4, r = l & 15;

  // XCD-aware bijective remap (T1): grid linear id -> contiguous chunk per XCD.
  const int nwg = gridDim.x * gridDim.y;               // always % 8 == 0 here
  const int lin = blockIdx.y * gridDim.x + blockIdx.x;
  const int lin2 = (lin & 7) * (nwg >> 3) + (lin >> 3);
  const int m0 = (lin2 / gridDim.x) * 128, n0 = (lin2 % gridDim.x) * 128;
  const int wm = w >> 1, wn = w & 1;

  f4v acc[4][4] = {};

  const int srow = 16 * w + (l >> 2);  // staging row within tile (+64 for issue 1)
  const int sc8 = 8 * (l & 3);         // staging col elem offset within BK=32

  const int nsteps = K >> 5;
  for (int ks = 0; ks < nsteps; ++ks) {
    const int kk = ks << 5;
    __syncthreads();  // all waves done reading LDS from previous step
    // ---- stage A ----
    if (AMODE == 0) {
      const short* a0 = A + ((size_t)(m0 + srow) * K + kk + sc8);
      gload16(a0, (char*)As + w * 1024);
      gload16(a0 + (size_t)64 * K, (char*)As + w * 1024 + 4096);
    } else {
      const int kw = ks / 24;                       // 768/32 = 24 steps per tap
      const int ii = (ks - kw * 24) * 32 + sc8;     // col within y
#pragma unroll
      for (int j = 0; j < 2; ++j) {
        int m = m0 + srow + 64 * j;
        int b = m >> 10, t = m & 1023;
        int lpos = 2 * t - 1 + kw;                  // in [-1, 2047]
        const short* a0 = (lpos < 0) ? (zp + sc8)
                                     : A + ((size_t)(b * 2048 + lpos) * 768 + ii);
        gload16(a0, (char*)As + w * 1024 + j * 4096);
      }
    }
    // ---- stage B ----
    {
      const short* b0 = Bt + ((size_t)(n0 + srow) * K + kk + sc8);
      gload16(b0, (char*)Bs + w * 1024);
      gload16(b0 + (size_t)64 * K, (char*)Bs + w * 1024 + 4096);
    }
    __syncthreads();  // compiler drains vmcnt(0) before barrier -> tiles ready
    // ---- compute ----
    s8v af[4], bfr[4];
#pragma unroll
    for (int mt = 0; mt < 4; ++mt)
      af[mt] = *(const s8v*)&As[(64 * wm + 16 * mt + r) * 32 + 8 * g];
#pragma unroll
    for (int nt = 0; nt < 4; ++nt)
      bfr[nt] = *(const s8v*)&Bs[(64 * wn + 16 * nt + r) * 32 + 8 * g];
#pragma unroll
    for (int mt = 0; mt < 4; ++mt)
#pragma unroll
      for (int nt = 0; nt < 4; ++nt)
        acc[mt][nt] = __builtin_amdgcn_mfma_f32_16x16x32_bf16(af[mt], bfr[nt],
                                                              acc[mt][nt], 0, 0, 0);
  }
  // ---- epilogue ----
#pragma unroll
  for (int nt = 0; nt < 4; ++nt) {
    const int col = n0 + 64 * wn + 16 * nt + r;
    const float bv = bias[col];
#pragma unroll
    for (int mt = 0; mt < 4; ++mt) {
#pragma unroll
      for (int i = 0; i < 4; ++i) {
        int row = m0 + 64 * wm + 16 * mt + 4 * g + i;
        float v = acc[mt][nt][i] + bv;
        if (EPI == 0) v = fmaxf(v, 0.f);
        if (EPI <= 1) {
          Cbf[(size_t)row * N + col] = f2bf(v);
        } else {
          int b = row >> 10, t = row & 1023;
          int h = col >> 6, dd = col & 63;
          float res = st[(((size_t)(b * 12 + h) * 2048) + 2 * t) * 64 + dd];
          Cf[(((size_t)(b * 12 + h) * 1024) + t) * 64 + dd] = v + res;
        }
      }
    }
  }
}

// ---------------- flash attention ----------------
// grid: B*H*16 blocks; block = (b,h, 64 q-rows); wave w owns 16 q-rows. KVBLK=64.
__global__ __launch_bounds__(256, 3)
void k_attn(const short* __restrict__ qb, const short* __restrict__ kb,
            const short* __restrict__ vt, short* __restrict__ ob) {
  __shared__ __align__(16) short Qs[64 * 64];     // [q][d], xor-swizzled 128B rows
  __shared__ __align__(16) short Ks[64 * 64];     // [j][d], swizzled
  __shared__ __align__(16) short Vts[64 * 64];    // [d][j], swizzled
  __shared__ __align__(16) short Ps[4][16 * 72];  // per-wave P[q][j], stride 72

  // XCD remap: 16 consecutive blocks share (b,h) -> keep them on one XCD.
  const int lin = blockIdx.x;
  const int blk = (lin & 7) * (1536 >> 3) + (lin >> 3);
  const int qblk = blk & 15, bh = blk >> 4;
  const int b = bh / 12, h = bh % 12;
  const int tid = threadIdx.x;
  const int w = tid >> 6, l = tid & 63;
  const int g = l >> 4, r = l & 15;

  const int row = tid >> 3, p = tid & 7;  // staging: 32 rows/issue, 8x16B chunks/row

  // stage Q (xor-swizzled 16B chunks within each 128B row)
#pragma unroll
  for (int j = 0; j < 2; ++j) {
    int rw = row + 32 * j;
    int c = p ^ (rw & 7);
    gload16(qb + ((size_t)(b * 1024 + qblk * 64 + rw) * 768 + h * 64 + 8 * c),
            (char*)Qs + w * 1024 + j * 4096);
  }
  __syncthreads();
  s8v qf[2];
#pragma unroll
  for (int c = 0; c < 2; ++c)
    qf[c] = *(const s8v*)&Qs[(16 * w + r) * 64 + 8 * ((4 * c + g) ^ (r & 7))];

  f4v oacc[4] = {};
  float mrun[4], lrun[4];
#pragma unroll
  for (int i = 0; i < 4; ++i) { mrun[i] = -1e30f; lrun[i] = 0.f; }

  for (int jb = 0; jb < 32; ++jb) {
    __syncthreads();  // previous tile fully consumed
#pragma unroll
    for (int iss = 0; iss < 2; ++iss) {
      int jr = row + 32 * iss;
      int c = p ^ (jr & 7);
      gload16(kb + ((size_t)(b * 2048 + jb * 64 + jr) * 768 + h * 64 + 8 * c),
              (char*)Ks + w * 1024 + iss * 4096);
      gload16(vt + ((size_t)(bh * 64 + jr) * 2048 + jb * 64 + 8 * c),
              (char*)Vts + w * 1024 + iss * 4096);
    }
    __syncthreads();

    // S = Q K^T  (C-frag: row q = 4g+i, col j = 16nt+r)
    f4v sacc[4] = {};
#pragma unroll
    for (int nt = 0; nt < 4; ++nt)
#pragma unroll
      for (int c = 0; c < 2; ++c) {
        s8v kf = *(const s8v*)&Ks[(16 * nt + r) * 64 + 8 * ((4 * c + g) ^ (r & 7))];
        sacc[nt] = __builtin_amdgcn_mfma_f32_16x16x32_bf16(qf[c], kf, sacc[nt], 0, 0, 0);
      }

    float alpha[4];
#pragma unroll
    for (int i = 0; i < 4; ++i) {
      float s0 = sacc[0][i] * 0.125f, s1 = sacc[1][i] * 0.125f;
      float s2 = sacc[2][i] * 0.125f, s3 = sacc[3][i] * 0.125f;
      float mx = fmaxf(fmaxf(s0, s1), fmaxf(s2, s3));
      mx = fmaxf(mx, __shfl_xor(mx, 1));
      mx = fmaxf(mx, __shfl_xor(mx, 2));
      mx = fmaxf(mx, __shfl_xor(mx, 4));
      mx = fmaxf(mx, __shfl_xor(mx, 8));
      float mn = fmaxf(mrun[i], mx);
      alpha[i] = __expf(mrun[i] - mn);
      mrun[i] = mn;
      float p0 = __expf(s0 - mn), p1 = __expf(s1 - mn);
      float p2 = __expf(s2 - mn), p3 = __expf(s3 - mn);
      float ps = (p0 + p1) + (p2 + p3);
      ps += __shfl_xor(ps, 1);
      ps += __shfl_xor(ps, 2);
      ps += __shfl_xor(ps, 4);
      ps += __shfl_xor(ps, 8);
      lrun[i] = lrun[i] * alpha[i] + ps;
      const int qr = (4 * g + i) * 72 + r;
      Ps[w][qr] = f2bf(p0);
      Ps[w][qr + 16] = f2bf(p1);
      Ps[w][qr + 32] = f2bf(p2);
      Ps[w][qr + 48] = f2bf(p3);
    }
#pragma unroll
    for (int nt = 0; nt < 4; ++nt)
#pragma unroll
      for (int i = 0; i < 4; ++i) oacc[nt][i] *= alpha[i];

    asm volatile("" ::: "memory");  // keep Ps writes ordered before re-read
    // P A-frag: row q = r, k(j) = 32kc + 8g..+7
    s8v pf[2];
#pragma unroll
    for (int kc = 0; kc < 2; ++kc)
      pf[kc] = *(const s8v*)&Ps[w][r * 72 + 32 * kc + 8 * g];
#pragma unroll
    for (int nt = 0; nt < 4; ++nt)
#pragma unroll
      for (int kc = 0; kc < 2; ++kc) {
        s8v vf = *(const s8v*)&Vts[(16 * nt + r) * 64 + 8 * ((4 * kc + g) ^ (r & 7))];
        oacc[nt] = __builtin_amdgcn_mfma_f32_16x16x32_bf16(pf[kc], vf, oacc[nt], 0, 0, 0);
      }
  }

  float inv[4];
#pragma unroll
  for (int i = 0; i < 4; ++i) inv[i] = 1.f / lrun[i];
#pragma unroll
  for (int nt = 0; nt < 4; ++nt)
#pragma unroll
    for (int i = 0; i < 4; ++i) {
      int q = qblk * 64 + 16 * w + 4 * g + i;
      ob[((size_t)(b * 1024 + q)) * 768 + h * 64 + 16 * nt + r] = f2bf(oacc[nt][i] * inv[i]);
    }
}

// ---------------- launch ----------------
extern "C" void kernel_launch(void* const* d_in, const int* in_sizes, int n_in,
                              void* d_out, int out_size, void* d_ws, size_t ws_size,
                              hipStream_t stream) {
  const float* state = (const float*)d_in[0];
  const float* Wi  = (const float*)d_in[1];
  const float* bi  = (const float*)d_in[2];
  const float* Wq  = (const float*)d_in[3];
  const float* bq  = (const float*)d_in[4];
  const float* Wk  = (const float*)d_in[5];
  const float* bk  = (const float*)d_in[6];
  const float* Wv  = (const float*)d_in[7];
  const float* bv  = (const float*)d_in[8];
  const float* Wao = (const float*)d_in[9];
  const float* bao = (const float*)d_in[10];
  const float* Wo  = (const float*)d_in[11];
  const float* bo  = (const float*)d_in[12];
  float* out = (float*)d_out;

  char* ws = (char*)d_ws;
  const size_t SZ = (size_t)16384 * 768 * 2;  // 25165824 B
  short* xbf = (short*)ws;                    // [B,L,E] bf16; reused later as vt
  short* y   = (short*)(ws + SZ);             // [B,L,E]; reused as attno/z1
  short* kbf = (short*)(ws + 2 * SZ);
  short* vbf = (short*)(ws + 3 * SZ);
  short* qbf = (short*)(ws + 4 * SZ);         // [B,Lq,E] = SZ/2
  char*  wp  = ws + 4 * SZ + SZ / 2;
  short* wib  = (short*)wp;
  short* wkb  = (short*)(wp + 1 * 1179648);
  short* wvb  = (short*)(wp + 2 * 1179648);
  short* waob = (short*)(wp + 3 * 1179648);
  short* wob  = (short*)(wp + 4 * 1179648);
  short* wqt  = (short*)(wp + 5 * 1179648);
  short* zp   = (short*)(wp + 5 * 1179648 + 3538944);
  short* vtb   = xbf;                // valid: xbf dead after GEMM1
  short* attno = y;                  // valid: y dead after q/k/v GEMMs
  short* z1    = (short*)((char*)y + SZ / 2);

  hipMemsetAsync(zp, 0, 256, stream);
  k_tr_state<<<6144, 256, 0, stream>>>(state, xbf);
  k_castw<<<288, 256, 0, stream>>>(Wi, wib);
  k_castw<<<288, 256, 0, stream>>>(Wk, wkb);
  k_castw<<<288, 256, 0, stream>>>(Wv, wvb);
  k_castw<<<288, 256, 0, stream>>>(Wao, waob);
  k_castw<<<288, 256, 0, stream>>>(Wo, wob);
  k_tr_wq<<<dim3(24, 24, 3), 256, 0, stream>>>(Wq, wqt);

  // y = relu(x @ Wi^T + bi)
  k_gemm<0, 0><<<dim3(6, 128), 256, 0, stream>>>(xbf, wib, bi, y, nullptr, nullptr, zp, 16384, 768, 768);
  // k, v
  k_gemm<0, 1><<<dim3(6, 128), 256, 0, stream>>>(y, wkb, bk, kbf, nullptr, nullptr, zp, 16384, 768, 768);
  k_gemm<0, 1><<<dim3(6, 128), 256, 0, stream>>>(y, wvb, bv, vbf, nullptr, nullptr, zp, 16384, 768, 768);
  // q = conv1d(y, Wq, stride 2, pad 1) + bq  (gathered GEMM, K = 2304)
  k_gemm<1, 1><<<dim3(6, 64), 256, 0, stream>>>(y, wqt, bq, qbf, nullptr, nullptr, zp, 8192, 768, 2304);
  // v transpose for PV fragment reads
  k_tr_v<<<dim3(64, 2, 96), 256, 0, stream>>>(vbf, vtb);
  // flash attention
  k_attn<<<1536, 256, 0, stream>>>(qbf, kbf, vtb, attno);
  // z1 = relu(attno @ Wao^T + bao)
  k_gemm<0, 0><<<dim3(6, 64), 256, 0, stream>>>(attno, waob, bao, z1, nullptr, nullptr, zp, 8192, 768, 768);
  // out = z1 @ Wo^T + bo + residual, reshaped to [B,H,Lq,D]
  k_gemm<0, 2><<<dim3(6, 64), 256, 0, stream>>>(z1, wob, bo, nullptr, out, state, zp, 8192, 768, 768);
}

// Round 3
// 438.858 us; speedup vs baseline: 1.1324x; 1.1324x over previous
//
#include <hip/hip_runtime.h>
#include <hip/hip_bf16.h>
#include <stdint.h>

#define DEVI __device__ __forceinline__

typedef short s8v __attribute__((ext_vector_type(8)));
typedef short s4v __attribute__((ext_vector_type(4)));
typedef float f4v __attribute__((ext_vector_type(4)));

DEVI short f2bf(float f) {
  unsigned u = __builtin_bit_cast(unsigned, f);
  u += 0x7FFFu + ((u >> 16) & 1u);
  return (short)(u >> 16);
}

DEVI void gload16(const void* g, void* l) {
  __builtin_amdgcn_global_load_lds((const __attribute__((address_space(1))) unsigned*)g,
                                   (__attribute__((address_space(3))) unsigned*)l,
                                   16, 0, 0);
}

// ---------------- prep kernels ----------------

// state [B,H,L,D] f32 -> xbf [B,L,E] bf16
__global__ __launch_bounds__(256) void k_tr_state(const float* __restrict__ st,
                                                  short* __restrict__ xbf) {
  int idx = blockIdx.x * 256 + threadIdx.x;      // 8*12*2048*8 threads
  int dc = idx & 7;
  int l  = (idx >> 3) & 2047;
  int hb = idx >> 14;                            // b*12 + h
  int h = hb % 12, b = hb / 12;
  const float* s = st + ((size_t)hb * 2048 + l) * 64 + dc * 8;
  f4v a = *(const f4v*)s;
  f4v c = *(const f4v*)(s + 4);
  short o[8];
#pragma unroll
  for (int j = 0; j < 4; ++j) { o[j] = f2bf(a[j]); o[4 + j] = f2bf(c[j]); }
  *(s8v*)(xbf + ((size_t)(b * 2048 + l)) * 768 + h * 64 + dc * 8) = *(s8v*)o;
}

// f32 -> bf16 elementwise (weights)
__global__ __launch_bounds__(256) void k_castw(const float* __restrict__ src,
                                               short* __restrict__ dst) {
  int idx = blockIdx.x * 256 + threadIdx.x;
  const float* s = src + (size_t)idx * 8;
  f4v a = *(const f4v*)s;
  f4v c = *(const f4v*)(s + 4);
  short o[8];
#pragma unroll
  for (int j = 0; j < 4; ++j) { o[j] = f2bf(a[j]); o[4 + j] = f2bf(c[j]); }
  *(s8v*)(dst + (size_t)idx * 8) = *(s8v*)o;
}

// Wq [3][768][768] f32 -> Wqt [768][2304] bf16 : Wqt[o][kw*768+i] = Wq[kw][i][o]
__global__ __launch_bounds__(256) void k_tr_wq(const float* __restrict__ wq,
                                               short* __restrict__ wqt) {
  __shared__ float tile[32][33];
  const int kw = blockIdx.z;
  const int i0 = blockIdx.y * 32, o0 = blockIdx.x * 32;
  const int tx = threadIdx.x & 31, ty = threadIdx.x >> 5;
#pragma unroll
  for (int rr = 0; rr < 32; rr += 8)
    tile[ty + rr][tx] = wq[((size_t)kw * 768 + i0 + ty + rr) * 768 + o0 + tx];
  __syncthreads();
#pragma unroll
  for (int rr = 0; rr < 32; rr += 8)
    wqt[(size_t)(o0 + ty + rr) * 2304 + kw * 768 + i0 + tx] = f2bf(tile[tx][ty + rr]);
}

// v [B,L,768] bf16 -> vt [96*64][2048] bf16 : vt[bh*64+d][l] = v[b][l][h*64+d]
__global__ __launch_bounds__(256) void k_tr_v(const short* __restrict__ v,
                                              short* __restrict__ vt) {
  __shared__ short tile[32][33];
  const int bh = blockIdx.z;
  const int l0 = blockIdx.x * 32, d0 = blockIdx.y * 32;
  const int b = bh / 12, h = bh % 12;
  const int tx = threadIdx.x & 31, ty = threadIdx.x >> 5;
#pragma unroll
  for (int rr = 0; rr < 32; rr += 8)
    tile[ty + rr][tx] = v[((size_t)(b * 2048 + l0 + ty + rr)) * 768 + h * 64 + d0 + tx];
  __syncthreads();
#pragma unroll
  for (int rr = 0; rr < 32; rr += 8)
    vt[((size_t)(bh * 64 + d0 + ty + rr)) * 2048 + l0 + tx] = tile[tx][ty + rr];
}

// ---------------- GEMM:  C = act(A @ Bt^T + bias) ----------------
// A [M,K] bf16 row-major (AMODE 1: conv-gathered view of y), Bt [N,K] bf16.
// EPI: 0 relu->bf16, 1 bf16, 2 final fp32 + strided residual.
template <int AMODE, int EPI>
__global__ __launch_bounds__(256, 2)
void k_gemm(const short* __restrict__ A, const short* __restrict__ Bt,
            const float* __restrict__ bias, short* __restrict__ Cbf,
            float* __restrict__ Cf, const float* __restrict__ st,
            const short* __restrict__ zp, int M, int N, int K) {
  __shared__ __align__(16) short As[128 * 32];
  __shared__ __align__(16) short Bs[128 * 32];
  const int tid = threadIdx.x;
  const int w = tid >> 6, l = tid & 63;
  const int g = l >> 4, r = l & 15;

  // XCD-aware bijective remap (T1): grid linear id -> contiguous chunk per XCD.
  const int nwg = gridDim.x * gridDim.y;               // always % 8 == 0 here
  const int lin = blockIdx.y * gridDim.x + blockIdx.x;
  const int lin2 = (lin & 7) * (nwg >> 3) + (lin >> 3);
  const int m0 = (lin2 / gridDim.x) * 128, n0 = (lin2 % gridDim.x) * 128;
  const int wm = w >> 1, wn = w & 1;

  f4v acc[4][4] = {};

  const int srow = 16 * w + (l >> 2);  // staging row within tile (+64 for issue 1)
  const int sc8 = 8 * (l & 3);         // staging col elem offset within BK=32

  const int nsteps = K >> 5;
  for (int ks = 0; ks < nsteps; ++ks) {
    const int kk = ks << 5;
    __syncthreads();  // all waves done reading LDS from previous step
    // ---- stage A ----
    if (AMODE == 0) {
      const short* a0 = A + ((size_t)(m0 + srow) * K + kk + sc8);
      gload16(a0, (char*)As + w * 1024);
      gload16(a0 + (size_t)64 * K, (char*)As + w * 1024 + 4096);
    } else {
      const int kw = ks / 24;                       // 768/32 = 24 steps per tap
      const int ii = (ks - kw * 24) * 32 + sc8;     // col within y
#pragma unroll
      for (int j = 0; j < 2; ++j) {
        int m = m0 + srow + 64 * j;
        int b = m >> 10, t = m & 1023;
        int lpos = 2 * t - 1 + kw;                  // in [-1, 2047]
        const short* a0 = (lpos < 0) ? (zp + sc8)
                                     : A + ((size_t)(b * 2048 + lpos) * 768 + ii);
        gload16(a0, (char*)As + w * 1024 + j * 4096);
      }
    }
    // ---- stage B ----
    {
      const short* b0 = Bt + ((size_t)(n0 + srow) * K + kk + sc8);
      gload16(b0, (char*)Bs + w * 1024);
      gload16(b0 + (size_t)64 * K, (char*)Bs + w * 1024 + 4096);
    }
    __syncthreads();  // compiler drains vmcnt(0) before barrier -> tiles ready
    // ---- compute ----
    s8v af[4], bfr[4];
#pragma unroll
    for (int mt = 0; mt < 4; ++mt)
      af[mt] = *(const s8v*)&As[(64 * wm + 16 * mt + r) * 32 + 8 * g];
#pragma unroll
    for (int nt = 0; nt < 4; ++nt)
      bfr[nt] = *(const s8v*)&Bs[(64 * wn + 16 * nt + r) * 32 + 8 * g];
#pragma unroll
    for (int mt = 0; mt < 4; ++mt)
#pragma unroll
      for (int nt = 0; nt < 4; ++nt)
        acc[mt][nt] = __builtin_amdgcn_mfma_f32_16x16x32_bf16(af[mt], bfr[nt],
                                                              acc[mt][nt], 0, 0, 0);
  }
  // ---- epilogue ----
#pragma unroll
  for (int nt = 0; nt < 4; ++nt) {
    const int col = n0 + 64 * wn + 16 * nt + r;
    const float bv = bias[col];
#pragma unroll
    for (int mt = 0; mt < 4; ++mt) {
#pragma unroll
      for (int i = 0; i < 4; ++i) {
        int row = m0 + 64 * wm + 16 * mt + 4 * g + i;
        float v = acc[mt][nt][i] + bv;
        if (EPI == 0) v = fmaxf(v, 0.f);
        if (EPI <= 1) {
          Cbf[(size_t)row * N + col] = f2bf(v);
        } else {
          int b = row >> 10, t = row & 1023;
          int h = col >> 6, dd = col & 63;
          float res = st[(((size_t)(b * 12 + h) * 2048) + 2 * t) * 64 + dd];
          Cf[(((size_t)(b * 12 + h) * 1024) + t) * 64 + dd] = v + res;
        }
      }
    }
  }
}

// ---------------- flash attention ----------------
// grid: B*H*16 blocks; block = (b,h, 64 q-rows); wave w owns q rows 16w..16w+15.
// Swapped-operand scheme: lane (g,r) owns q-row = qblk*64+16w+r throughout.
//   QK^T: sacc[nt] = mfma(K_frag, Q_frag) -> sacc[nt][i] = S[q=r][j=16nt+4g+i]
//   PV  : oacc[mt] = mfma(Vt_frag, P_frag) -> oacc[mt][i] = O[q=r][d=16mt+4g+i]
// => softmax m/l/alpha and final 1/l are lane-local scalars; 4 shfl_xor per tile.
// K/V double-buffered (T3 2-phase): STAGE(next) -> compute(cur) -> vmcnt(0) -> barrier.
__global__ __launch_bounds__(256, 3)
void k_attn(const short* __restrict__ qb, const short* __restrict__ kb,
            const short* __restrict__ vt, short* __restrict__ ob) {
  __shared__ __align__(16) short Ks[2][64 * 64];   // [j][d], xor-swizzled 128B rows
  __shared__ __align__(16) short Vts[2][64 * 64];  // [d][j], swizzled
  __shared__ __align__(16) short Ps[4][16 * 72];   // per-wave P[q][j], stride 72

  // XCD remap: 16 consecutive blocks share (b,h) -> keep them on one XCD.
  const int lin = blockIdx.x;
  const int blk = (lin & 7) * 192 + (lin >> 3);
  const int qblk = blk & 15, bh = blk >> 4;
  const int b = bh / 12, h = bh % 12;
  const int tid = threadIdx.x;
  const int w = tid >> 6, l = tid & 63;
  const int g = l >> 4, r = l & 15;
  const int row = tid >> 3, p = tid & 7;  // staging: 32 rows/issue, 8x16B chunks/row

  // Q B-fragments straight from global (once per block; no LDS round-trip).
  const short* qrow = qb + ((size_t)(b * 1024 + qblk * 64 + 16 * w + r)) * 768 + h * 64;
  s8v qf[2];
  qf[0] = *(const s8v*)(qrow + 8 * g);
  qf[1] = *(const s8v*)(qrow + 32 + 8 * g);

  auto STAGE = [&](int buf, int jb) {
#pragma unroll
    for (int iss = 0; iss < 2; ++iss) {
      int jr = row + 32 * iss;
      int c = p ^ (jr & 7);
      gload16(kb + ((size_t)(b * 2048 + jb * 64 + jr)) * 768 + h * 64 + 8 * c,
              (char*)Ks[buf] + iss * 4096 + w * 1024);
      gload16(vt + ((size_t)(bh * 64 + jr)) * 2048 + jb * 64 + 8 * c,
              (char*)Vts[buf] + iss * 4096 + w * 1024);
    }
  };

  f4v oacc[4] = {};
  float mrun = -3.0e38f, lrun = 0.f;

  STAGE(0, 0);
  asm volatile("s_waitcnt vmcnt(0)" ::: "memory");
  __builtin_amdgcn_s_barrier();

  for (int jb = 0; jb < 32; ++jb) {
    const int cur = jb & 1;
    if (jb < 31) STAGE(cur ^ 1, jb + 1);  // prefetch next tile (in flight over compute)

    // S^T = K Q^T
    f4v sacc[4] = {};
#pragma unroll
    for (int nt = 0; nt < 4; ++nt)
#pragma unroll
      for (int c = 0; c < 2; ++c) {
        s8v kf = *(const s8v*)&Ks[cur][(16 * nt + r) * 64 + 8 * ((4 * c + g) ^ (r & 7))];
        sacc[nt] = __builtin_amdgcn_mfma_f32_16x16x32_bf16(kf, qf[c], sacc[nt], 0, 0, 0);
      }

    // lane-local online softmax for q=r (16 j's per lane, cross-g reduce)
    float s[16];
    float mx = -3.0e38f;
#pragma unroll
    for (int nt = 0; nt < 4; ++nt)
#pragma unroll
      for (int i = 0; i < 4; ++i) {
        s[4 * nt + i] = sacc[nt][i] * 0.125f;
        mx = fmaxf(mx, s[4 * nt + i]);
      }
    mx = fmaxf(mx, __shfl_xor(mx, 16));
    mx = fmaxf(mx, __shfl_xor(mx, 32));

    bool defer = __all(mx <= mrun + 8.0f);  // T13: skip rescale when max barely grows
    float mn = defer ? mrun : fmaxf(mrun, mx);
    float alpha = defer ? 1.0f : __expf(mrun - mn);
    mrun = mn;

    float ls = 0.f;
#pragma unroll
    for (int k = 0; k < 8; ++k) {
      float p0 = __expf(s[2 * k] - mn);
      float p1 = __expf(s[2 * k + 1] - mn);
      ls += p0 + p1;
      unsigned pw = ((unsigned)(unsigned short)f2bf(p1) << 16) |
                    (unsigned)(unsigned short)f2bf(p0);
      // pair k = 2*nt + t -> j base = 16*nt + 4*g + 2*t
      *(unsigned*)&Ps[w][r * 72 + 16 * (k >> 1) + 4 * g + 2 * (k & 1)] = pw;
    }
    ls += __shfl_xor(ls, 16);
    ls += __shfl_xor(ls, 32);
    lrun = lrun * alpha + ls;
    if (!defer) {
#pragma unroll
      for (int mt = 0; mt < 4; ++mt)
#pragma unroll
        for (int i = 0; i < 4; ++i) oacc[mt][i] *= alpha;
    }

    asm volatile("" ::: "memory");  // keep Ps writes ordered before re-read
    s8v pf[2];
#pragma unroll
    for (int kc = 0; kc < 2; ++kc)
      pf[kc] = *(const s8v*)&Ps[w][r * 72 + 32 * kc + 8 * g];
    // O^T = V^T P^T
#pragma unroll
    for (int mt = 0; mt < 4; ++mt)
#pragma unroll
      for (int kc = 0; kc < 2; ++kc) {
        s8v vf = *(const s8v*)&Vts[cur][(16 * mt + r) * 64 + 8 * ((4 * kc + g) ^ (r & 7))];
        oacc[mt] = __builtin_amdgcn_mfma_f32_16x16x32_bf16(vf, pf[kc], oacc[mt], 0, 0, 0);
      }

    asm volatile("s_waitcnt vmcnt(0)" ::: "memory");  // next tile landed
    __builtin_amdgcn_s_barrier();
  }

  const float inv = 1.f / lrun;
  short* obase = ob + ((size_t)(b * 1024 + qblk * 64 + 16 * w + r)) * 768 + h * 64;
#pragma unroll
  for (int mt = 0; mt < 4; ++mt) {
    short o4[4];
#pragma unroll
    for (int i = 0; i < 4; ++i) o4[i] = f2bf(oacc[mt][i] * inv);
    *(s4v*)(obase + 16 * mt + 4 * g) = *(s4v*)o4;
  }
}

// ---------------- launch ----------------
extern "C" void kernel_launch(void* const* d_in, const int* in_sizes, int n_in,
                              void* d_out, int out_size, void* d_ws, size_t ws_size,
                              hipStream_t stream) {
  const float* state = (const float*)d_in[0];
  const float* Wi  = (const float*)d_in[1];
  const float* bi  = (const float*)d_in[2];
  const float* Wq  = (const float*)d_in[3];
  const float* bq  = (const float*)d_in[4];
  const float* Wk  = (const float*)d_in[5];
  const float* bk  = (const float*)d_in[6];
  const float* Wv  = (const float*)d_in[7];
  const float* bv  = (const float*)d_in[8];
  const float* Wao = (const float*)d_in[9];
  const float* bao = (const float*)d_in[10];
  const float* Wo  = (const float*)d_in[11];
  const float* bo  = (const float*)d_in[12];
  float* out = (float*)d_out;

  char* ws = (char*)d_ws;
  const size_t SZ = (size_t)16384 * 768 * 2;  // 25165824 B
  short* xbf = (short*)ws;                    // [B,L,E] bf16; reused later as vt
  short* y   = (short*)(ws + SZ);             // [B,L,E]; reused as attno/z1
  short* kbf = (short*)(ws + 2 * SZ);
  short* vbf = (short*)(ws + 3 * SZ);
  short* qbf = (short*)(ws + 4 * SZ);         // [B,Lq,E] = SZ/2
  char*  wp  = ws + 4 * SZ + SZ / 2;
  short* wib  = (short*)wp;
  short* wkb  = (short*)(wp + 1 * 1179648);
  short* wvb  = (short*)(wp + 2 * 1179648);
  short* waob = (short*)(wp + 3 * 1179648);
  short* wob  = (short*)(wp + 4 * 1179648);
  short* wqt  = (short*)(wp + 5 * 1179648);
  short* zp   = (short*)(wp + 5 * 1179648 + 3538944);
  short* vtb   = xbf;                // valid: xbf dead after GEMM1
  short* attno = y;                  // valid: y dead after q/k/v GEMMs
  short* z1    = (short*)((char*)y + SZ / 2);

  hipMemsetAsync(zp, 0, 256, stream);
  k_tr_state<<<6144, 256, 0, stream>>>(state, xbf);
  k_castw<<<288, 256, 0, stream>>>(Wi, wib);
  k_castw<<<288, 256, 0, stream>>>(Wk, wkb);
  k_castw<<<288, 256, 0, stream>>>(Wv, wvb);
  k_castw<<<288, 256, 0, stream>>>(Wao, waob);
  k_castw<<<288, 256, 0, stream>>>(Wo, wob);
  k_tr_wq<<<dim3(24, 24, 3), 256, 0, stream>>>(Wq, wqt);

  // y = relu(x @ Wi^T + bi)
  k_gemm<0, 0><<<dim3(6, 128), 256, 0, stream>>>(xbf, wib, bi, y, nullptr, nullptr, zp, 16384, 768, 768);
  // k, v
  k_gemm<0, 1><<<dim3(6, 128), 256, 0, stream>>>(y, wkb, bk, kbf, nullptr, nullptr, zp, 16384, 768, 768);
  k_gemm<0, 1><<<dim3(6, 128), 256, 0, stream>>>(y, wvb, bv, vbf, nullptr, nullptr, zp, 16384, 768, 768);
  // q = conv1d(y, Wq, stride 2, pad 1) + bq  (gathered GEMM, K = 2304)
  k_gemm<1, 1><<<dim3(6, 64), 256, 0, stream>>>(y, wqt, bq, qbf, nullptr, nullptr, zp, 8192, 768, 2304);
  // v transpose for PV fragment reads
  k_tr_v<<<dim3(64, 2, 96), 256, 0, stream>>>(vbf, vtb);
  // flash attention
  k_attn<<<1536, 256, 0, stream>>>(qbf, kbf, vtb, attno);
  // z1 = relu(attno @ Wao^T + bao)
  k_gemm<0, 0><<<dim3(6, 64), 256, 0, stream>>>(attno, waob, bao, z1, nullptr, nullptr, zp, 8192, 768, 768);
  // out = z1 @ Wo^T + bo + residual, reshaped to [B,H,Lq,D]
  k_gemm<0, 2><<<dim3(6, 64), 256, 0, stream>>>(z1, wob, bo, nullptr, out, state, zp, 8192, 768, 768);
}

// Round 4
// 423.924 us; speedup vs baseline: 1.1722x; 1.0352x over previous
//
#include <hip/hip_runtime.h>
#include <hip/hip_bf16.h>
#include <stdint.h>

#define DEVI __device__ __forceinline__

typedef short s8v __attribute__((ext_vector_type(8)));
typedef short s4v __attribute__((ext_vector_type(4)));
typedef float f4v __attribute__((ext_vector_type(4)));

DEVI short f2bf(float f) {
  unsigned u = __builtin_bit_cast(unsigned, f);
  u += 0x7FFFu + ((u >> 16) & 1u);
  return (short)(u >> 16);
}

DEVI unsigned cvtpk(float lo, float hi) {  // dword = [lo | hi<<16] as bf16 pair
  unsigned r;
  asm("v_cvt_pk_bf16_f32 %0, %1, %2" : "=v"(r) : "v"(lo), "v"(hi));
  return r;
}

DEVI void gload16(const void* g, void* l) {
  __builtin_amdgcn_global_load_lds((const __attribute__((address_space(1))) unsigned*)g,
                                   (__attribute__((address_space(3))) unsigned*)l,
                                   16, 0, 0);
}

// ---------------- prep kernels ----------------

// state [B,H,L,D] f32 -> xbf [B,L,E] bf16
__global__ __launch_bounds__(256) void k_tr_state(const float* __restrict__ st,
                                                  short* __restrict__ xbf) {
  int idx = blockIdx.x * 256 + threadIdx.x;      // 8*12*2048*8 threads
  int dc = idx & 7;
  int l  = (idx >> 3) & 2047;
  int hb = idx >> 14;                            // b*12 + h
  int h = hb % 12, b = hb / 12;
  const float* s = st + ((size_t)hb * 2048 + l) * 64 + dc * 8;
  f4v a = *(const f4v*)s;
  f4v c = *(const f4v*)(s + 4);
  short o[8];
#pragma unroll
  for (int j = 0; j < 4; ++j) { o[j] = f2bf(a[j]); o[4 + j] = f2bf(c[j]); }
  *(s8v*)(xbf + ((size_t)(b * 2048 + l)) * 768 + h * 64 + dc * 8) = *(s8v*)o;
}

// f32 -> bf16 elementwise (weights), optional scale
__global__ __launch_bounds__(256) void k_castw(const float* __restrict__ src,
                                               short* __restrict__ dst, float sc) {
  int idx = blockIdx.x * 256 + threadIdx.x;
  const float* s = src + (size_t)idx * 8;
  f4v a = *(const f4v*)s;
  f4v c = *(const f4v*)(s + 4);
  short o[8];
#pragma unroll
  for (int j = 0; j < 4; ++j) { o[j] = f2bf(a[j] * sc); o[4 + j] = f2bf(c[j] * sc); }
  *(s8v*)(dst + (size_t)idx * 8) = *(s8v*)o;
}

// fused K|V bias: bkv[0:768) = bk*0.125, bkv[768:1536) = bv
__global__ __launch_bounds__(256) void k_bkv(const float* __restrict__ bk,
                                             const float* __restrict__ bv,
                                             float* __restrict__ bkv) {
  int i = blockIdx.x * 256 + threadIdx.x;
  bkv[i] = (i < 768) ? bk[i] * 0.125f : bv[i - 768];
}

// Wq [3][768][768] f32 -> Wqt [768][2304] bf16 : Wqt[o][kw*768+i] = Wq[kw][i][o]
__global__ __launch_bounds__(256) void k_tr_wq(const float* __restrict__ wq,
                                               short* __restrict__ wqt) {
  __shared__ float tile[32][33];
  const int kw = blockIdx.z;
  const int i0 = blockIdx.y * 32, o0 = blockIdx.x * 32;
  const int tx = threadIdx.x & 31, ty = threadIdx.x >> 5;
#pragma unroll
  for (int rr = 0; rr < 32; rr += 8)
    tile[ty + rr][tx] = wq[((size_t)kw * 768 + i0 + ty + rr) * 768 + o0 + tx];
  __syncthreads();
#pragma unroll
  for (int rr = 0; rr < 32; rr += 8)
    wqt[(size_t)(o0 + ty + rr) * 2304 + kw * 768 + i0 + tx] = f2bf(tile[tx][ty + rr]);
}

// v rows (stride `vs`) -> vt [96*64][2048] bf16 : vt[bh*64+d][l] = v[b][l][d]
__global__ __launch_bounds__(256) void k_tr_v(const short* __restrict__ v,
                                              short* __restrict__ vt, int vs) {
  __shared__ short tile[32][33];
  const int bh = blockIdx.z;
  const int l0 = blockIdx.x * 32, d0 = blockIdx.y * 32;
  const int b = bh / 12, h = bh % 12;
  const int tx = threadIdx.x & 31, ty = threadIdx.x >> 5;
#pragma unroll
  for (int rr = 0; rr < 32; rr += 8)
    tile[ty + rr][tx] = v[((size_t)(b * 2048 + l0 + ty + rr)) * vs + h * 64 + d0 + tx];
  __syncthreads();
#pragma unroll
  for (int rr = 0; rr < 32; rr += 8)
    vt[((size_t)(bh * 64 + d0 + ty + rr)) * 2048 + l0 + tx] = tile[tx][ty + rr];
}

// ---------------- GEMM:  C = act(A @ Bt^T + bias) ----------------
// A [M,K] bf16 row-major (AMODE 1: conv-gathered view of y), Bt [N,K] bf16.
// EPI: 0 relu->bf16, 1 bf16, 2 final fp32 + strided residual.
template <int AMODE, int EPI>
__global__ __launch_bounds__(256, 2)
void k_gemm(const short* __restrict__ A, const short* __restrict__ Bt,
            const float* __restrict__ bias, short* __restrict__ Cbf,
            float* __restrict__ Cf, const float* __restrict__ st,
            const short* __restrict__ zp, int M, int N, int K) {
  __shared__ __align__(16) short As[128 * 32];
  __shared__ __align__(16) short Bs[128 * 32];
  const int tid = threadIdx.x;
  const int w = tid >> 6, l = tid & 63;
  const int g = l >> 4, r = l & 15;

  // XCD-aware bijective remap (T1): grid linear id -> contiguous chunk per XCD.
  const int nwg = gridDim.x * gridDim.y;               // always % 8 == 0 here
  const int lin = blockIdx.y * gridDim.x + blockIdx.x;
  const int lin2 = (lin & 7) * (nwg >> 3) + (lin >> 3);
  const int m0 = (lin2 / gridDim.x) * 128, n0 = (lin2 % gridDim.x) * 128;
  const int wm = w >> 1, wn = w & 1;

  f4v acc[4][4] = {};

  const int srow = 16 * w + (l >> 2);  // staging row within tile (+64 for issue 1)
  const int sc8 = 8 * (l & 3);         // staging col elem offset within BK=32

  const int nsteps = K >> 5;
  for (int ks = 0; ks < nsteps; ++ks) {
    const int kk = ks << 5;
    __syncthreads();  // all waves done reading LDS from previous step
    // ---- stage A ----
    if (AMODE == 0) {
      const short* a0 = A + ((size_t)(m0 + srow) * K + kk + sc8);
      gload16(a0, (char*)As + w * 1024);
      gload16(a0 + (size_t)64 * K, (char*)As + w * 1024 + 4096);
    } else {
      const int kw = ks / 24;                       // 768/32 = 24 steps per tap
      const int ii = (ks - kw * 24) * 32 + sc8;     // col within y
#pragma unroll
      for (int j = 0; j < 2; ++j) {
        int m = m0 + srow + 64 * j;
        int b = m >> 10, t = m & 1023;
        int lpos = 2 * t - 1 + kw;                  // in [-1, 2047]
        const short* a0 = (lpos < 0) ? (zp + sc8)
                                     : A + ((size_t)(b * 2048 + lpos) * 768 + ii);
        gload16(a0, (char*)As + w * 1024 + j * 4096);
      }
    }
    // ---- stage B ----
    {
      const short* b0 = Bt + ((size_t)(n0 + srow) * K + kk + sc8);
      gload16(b0, (char*)Bs + w * 1024);
      gload16(b0 + (size_t)64 * K, (char*)Bs + w * 1024 + 4096);
    }
    __syncthreads();  // compiler drains vmcnt(0) before barrier -> tiles ready
    // ---- compute ----
    s8v af[4], bfr[4];
#pragma unroll
    for (int mt = 0; mt < 4; ++mt)
      af[mt] = *(const s8v*)&As[(64 * wm + 16 * mt + r) * 32 + 8 * g];
#pragma unroll
    for (int nt = 0; nt < 4; ++nt)
      bfr[nt] = *(const s8v*)&Bs[(64 * wn + 16 * nt + r) * 32 + 8 * g];
#pragma unroll
    for (int mt = 0; mt < 4; ++mt)
#pragma unroll
      for (int nt = 0; nt < 4; ++nt)
        acc[mt][nt] = __builtin_amdgcn_mfma_f32_16x16x32_bf16(af[mt], bfr[nt],
                                                              acc[mt][nt], 0, 0, 0);
  }
  // ---- epilogue ----
#pragma unroll
  for (int nt = 0; nt < 4; ++nt) {
    const int col = n0 + 64 * wn + 16 * nt + r;
    const float bv = bias[col];
#pragma unroll
    for (int mt = 0; mt < 4; ++mt) {
#pragma unroll
      for (int i = 0; i < 4; ++i) {
        int row = m0 + 64 * wm + 16 * mt + 4 * g + i;
        float v = acc[mt][nt][i] + bv;
        if (EPI == 0) v = fmaxf(v, 0.f);
        if (EPI <= 1) {
          Cbf[(size_t)row * N + col] = f2bf(v);
        } else {
          int b = row >> 10, t = row & 1023;
          int h = col >> 6, dd = col & 63;
          float res = st[(((size_t)(b * 12 + h) * 2048) + 2 * t) * 64 + dd];
          Cf[(((size_t)(b * 12 + h) * 1024) + t) * 64 + dd] = v + res;
        }
      }
    }
  }
}

// ---------------- flash attention ----------------
// grid: B*H*16 blocks; block = (b,h, 64 q-rows); wave w owns q rows 16w..16w+15.
// Lane (g,r) owns q-row = qblk*64+16w+r. K pre-scaled by 0.125 at weight cast.
//   QK^T: sacc[nt] = mfma(K_frag, Q_frag) -> sacc[nt][i] = S[j=16nt+4g+i][q=r]
//   PV  : oacc[mt] = mfma(Vt_frag, P_frag) -> oacc[mt][i] = O[d=16mt+4g+i][q=r]
// Ps: per-wave [16 q][64 j] bf16, 128B rows of 8 16B-chunks, chunk rotated by +r
// (additive rotation -> 2-way read banks; total LDS = 40960 B = 4 blocks/CU).
__global__ __launch_bounds__(256, 4)
void k_attn(const short* __restrict__ qb, const short* __restrict__ kvb,
            const short* __restrict__ vt, short* __restrict__ ob) {
  __shared__ __align__(16) short Ks[2][64 * 64];   // [j][d], xor-swizzled 128B rows
  __shared__ __align__(16) short Vts[2][64 * 64];  // [d][j], swizzled
  __shared__ __align__(16) short Ps[4][16 * 64];   // rotated chunks, stride 64

  // XCD remap: 16 consecutive blocks share (b,h) -> keep them on one XCD.
  const int lin = blockIdx.x;
  const int blk = (lin & 7) * 192 + (lin >> 3);
  const int qblk = blk & 15, bh = blk >> 4;
  const int b = bh / 12, h = bh % 12;
  const int tid = threadIdx.x;
  const int w = tid >> 6, l = tid & 63;
  const int g = l >> 4, r = l & 15;
  const int row = tid >> 3, p = tid & 7;  // staging: 32 rows/issue, 8x16B chunks/row

  // Q B-fragments straight from global (once per block; no LDS round-trip).
  const short* qrow = qb + ((size_t)(b * 1024 + qblk * 64 + 16 * w + r)) * 768 + h * 64;
  s8v qf[2];
  qf[0] = *(const s8v*)(qrow + 8 * g);
  qf[1] = *(const s8v*)(qrow + 32 + 8 * g);

  // Precomputed Ps write/read addresses (loop-invariant; chunk = +r rotation).
  unsigned* pswr[8];
#pragma unroll
  for (int k = 0; k < 8; ++k) {
    const int nt = k >> 1, t = k & 1;
    pswr[k] = (unsigned*)&Ps[w][r * 64 + 8 * ((2 * nt + (g >> 1) + r) & 7) +
                               4 * (g & 1) + 2 * t];
  }
  const s8v* psrd[2];
#pragma unroll
  for (int kc = 0; kc < 2; ++kc)
    psrd[kc] = (const s8v*)&Ps[w][r * 64 + 8 * ((4 * kc + g + r) & 7)];

  auto STAGE = [&](int buf, int jb) {
#pragma unroll
    for (int iss = 0; iss < 2; ++iss) {
      int jr = row + 32 * iss;
      int c = p ^ (jr & 7);
      gload16(kvb + ((size_t)(b * 2048 + jb * 64 + jr)) * 1536 + h * 64 + 8 * c,
              (char*)Ks[buf] + iss * 4096 + w * 1024);
      gload16(vt + ((size_t)(bh * 64 + jr)) * 2048 + jb * 64 + 8 * c,
              (char*)Vts[buf] + iss * 4096 + w * 1024);
    }
  };

  f4v oacc[4] = {};
  float mrun = -3.0e38f, lrun = 0.f;

  STAGE(0, 0);
  asm volatile("s_waitcnt vmcnt(0)" ::: "memory");
  __builtin_amdgcn_s_barrier();

  for (int jb = 0; jb < 32; ++jb) {
    const int cur = jb & 1;
    if (jb < 31) STAGE(cur ^ 1, jb + 1);  // prefetch next tile (in flight over compute)

    // S^T = K Q^T  (K already carries the 1/8 scale)
    f4v sacc[4] = {};
#pragma unroll
    for (int nt = 0; nt < 4; ++nt)
#pragma unroll
      for (int c = 0; c < 2; ++c) {
        s8v kf = *(const s8v*)&Ks[cur][(16 * nt + r) * 64 + 8 * ((4 * c + g) ^ (r & 7))];
        sacc[nt] = __builtin_amdgcn_mfma_f32_16x16x32_bf16(kf, qf[c], sacc[nt], 0, 0, 0);
      }

    // lane-local online softmax for q=r (16 j's per lane, cross-g reduce)
    float s[16];
#pragma unroll
    for (int nt = 0; nt < 4; ++nt)
#pragma unroll
      for (int i = 0; i < 4; ++i) s[4 * nt + i] = sacc[nt][i];
    float m01 = fmaxf(fmaxf(s[0], s[1]), fmaxf(s[2], s[3]));
    float m23 = fmaxf(fmaxf(s[4], s[5]), fmaxf(s[6], s[7]));
    float m45 = fmaxf(fmaxf(s[8], s[9]), fmaxf(s[10], s[11]));
    float m67 = fmaxf(fmaxf(s[12], s[13]), fmaxf(s[14], s[15]));
    float mx = fmaxf(fmaxf(m01, m23), fmaxf(m45, m67));
    mx = fmaxf(mx, __shfl_xor(mx, 16));
    mx = fmaxf(mx, __shfl_xor(mx, 32));

    bool defer = __all(mx <= mrun + 8.0f);  // T13: skip rescale when max barely grows
    float mn = defer ? mrun : fmaxf(mrun, mx);
    float alpha = defer ? 1.0f : __expf(mrun - mn);
    mrun = mn;

    float ls = 0.f;
#pragma unroll
    for (int k = 0; k < 8; ++k) {
      float p0 = __expf(s[2 * k] - mn);
      float p1 = __expf(s[2 * k + 1] - mn);
      ls += p0 + p1;
      *pswr[k] = cvtpk(p0, p1);  // bf16 pair, T12 primitive
    }
    ls += __shfl_xor(ls, 16);
    ls += __shfl_xor(ls, 32);
    lrun = lrun * alpha + ls;
    if (!defer) {
#pragma unroll
      for (int mt = 0; mt < 4; ++mt)
#pragma unroll
        for (int i = 0; i < 4; ++i) oacc[mt][i] *= alpha;
    }

    asm volatile("" ::: "memory");  // keep Ps writes ordered before re-read
    s8v pf0 = *psrd[0], pf1 = *psrd[1];
    // O^T = V^T P^T
#pragma unroll
    for (int mt = 0; mt < 4; ++mt) {
      s8v vf0 = *(const s8v*)&Vts[cur][(16 * mt + r) * 64 + 8 * ((g) ^ (r & 7))];
      s8v vf1 = *(const s8v*)&Vts[cur][(16 * mt + r) * 64 + 8 * ((4 + g) ^ (r & 7))];
      oacc[mt] = __builtin_amdgcn_mfma_f32_16x16x32_bf16(vf0, pf0, oacc[mt], 0, 0, 0);
      oacc[mt] = __builtin_amdgcn_mfma_f32_16x16x32_bf16(vf1, pf1, oacc[mt], 0, 0, 0);
    }

    asm volatile("s_waitcnt vmcnt(0)" ::: "memory");  // next tile landed
    __builtin_amdgcn_s_barrier();
  }

  const float inv = 1.f / lrun;
  short* obase = ob + ((size_t)(b * 1024 + qblk * 64 + 16 * w + r)) * 768 + h * 64;
#pragma unroll
  for (int mt = 0; mt < 4; ++mt) {
    uint2 uu;
    uu.x = cvtpk(oacc[mt][0] * inv, oacc[mt][1] * inv);
    uu.y = cvtpk(oacc[mt][2] * inv, oacc[mt][3] * inv);
    *(uint2*)(obase + 16 * mt + 4 * g) = uu;
  }
}

// ---------------- launch ----------------
extern "C" void kernel_launch(void* const* d_in, const int* in_sizes, int n_in,
                              void* d_out, int out_size, void* d_ws, size_t ws_size,
                              hipStream_t stream) {
  const float* state = (const float*)d_in[0];
  const float* Wi  = (const float*)d_in[1];
  const float* bi  = (const float*)d_in[2];
  const float* Wq  = (const float*)d_in[3];
  const float* bq  = (const float*)d_in[4];
  const float* Wk  = (const float*)d_in[5];
  const float* bk  = (const float*)d_in[6];
  const float* Wv  = (const float*)d_in[7];
  const float* bv  = (const float*)d_in[8];
  const float* Wao = (const float*)d_in[9];
  const float* bao = (const float*)d_in[10];
  const float* Wo  = (const float*)d_in[11];
  const float* bo  = (const float*)d_in[12];
  float* out = (float*)d_out;

  char* ws = (char*)d_ws;
  const size_t SZ = (size_t)16384 * 768 * 2;  // 25165824 B
  short* xbf = (short*)ws;                    // [B,L,E] bf16; reused later as vt
  short* y   = (short*)(ws + SZ);             // [B,L,E]; reused as attno/z1
  short* kvbf = (short*)(ws + 2 * SZ);        // fused [16384][1536]: K|V
  short* qbf = (short*)(ws + 4 * SZ);         // [B,Lq,E] = SZ/2
  char*  wp  = ws + 4 * SZ + SZ / 2;
  short* wib  = (short*)wp;
  short* wkb  = (short*)(wp + 1 * 1179648);   // wkb|wvb contiguous = fused Bt
  short* wvb  = (short*)(wp + 2 * 1179648);
  short* waob = (short*)(wp + 3 * 1179648);
  short* wob  = (short*)(wp + 4 * 1179648);
  short* wqt  = (short*)(wp + 5 * 1179648);
  short* zp   = (short*)(wp + 5 * 1179648 + 3538944);
  float* bkv  = (float*)(wp + 5 * 1179648 + 3538944 + 512);
  short* vtb   = xbf;                // valid: xbf dead after GEMM1
  short* attno = y;                  // valid: y dead after q/kv GEMMs
  short* z1    = (short*)((char*)y + SZ / 2);

  hipMemsetAsync(zp, 0, 256, stream);
  k_tr_state<<<6144, 256, 0, stream>>>(state, xbf);
  k_castw<<<288, 256, 0, stream>>>(Wi, wib, 1.0f);
  k_castw<<<288, 256, 0, stream>>>(Wk, wkb, 0.125f);  // fold 1/sqrt(d) into K
  k_castw<<<288, 256, 0, stream>>>(Wv, wvb, 1.0f);
  k_castw<<<288, 256, 0, stream>>>(Wao, waob, 1.0f);
  k_castw<<<288, 256, 0, stream>>>(Wo, wob, 1.0f);
  k_bkv<<<6, 256, 0, stream>>>(bk, bv, bkv);
  k_tr_wq<<<dim3(24, 24, 3), 256, 0, stream>>>(Wq, wqt);

  // y = relu(x @ Wi^T + bi)
  k_gemm<0, 0><<<dim3(6, 128), 256, 0, stream>>>(xbf, wib, bi, y, nullptr, nullptr, zp, 16384, 768, 768);
  // fused k|v = y @ [Wk*0.125; Wv]^T + [bk*0.125; bv]
  k_gemm<0, 1><<<dim3(12, 128), 256, 0, stream>>>(y, wkb, bkv, kvbf, nullptr, nullptr, zp, 16384, 1536, 768);
  // q = conv1d(y, Wq, stride 2, pad 1) + bq  (gathered GEMM, K = 2304)
  k_gemm<1, 1><<<dim3(6, 64), 256, 0, stream>>>(y, wqt, bq, qbf, nullptr, nullptr, zp, 8192, 768, 2304);
  // v transpose for PV fragment reads (reads V half of kvbf)
  k_tr_v<<<dim3(64, 2, 96), 256, 0, stream>>>(kvbf + 768, vtb, 1536);
  // flash attention
  k_attn<<<1536, 256, 0, stream>>>(qbf, kvbf, vtb, attno);
  // z1 = relu(attno @ Wao^T + bao)
  k_gemm<0, 0><<<dim3(6, 64), 256, 0, stream>>>(attno, waob, bao, z1, nullptr, nullptr, zp, 8192, 768, 768);
  // out = z1 @ Wo^T + bo + residual, reshaped to [B,H,Lq,D]
  k_gemm<0, 2><<<dim3(6, 64), 256, 0, stream>>>(z1, wob, bo, nullptr, out, state, zp, 8192, 768, 768);
}

// Round 7
// 409.372 us; speedup vs baseline: 1.2139x; 1.0355x over previous
//
#include <hip/hip_runtime.h>
#include <hip/hip_bf16.h>
#include <stdint.h>

#define DEVI __device__ __forceinline__

typedef short s8v __attribute__((ext_vector_type(8)));
typedef short s4v __attribute__((ext_vector_type(4)));
typedef float f4v __attribute__((ext_vector_type(4)));

#define KSCALE 0.18033688011112042f  // 0.125 * log2(e): QK^T lands in log2 domain
#define DEFTHR 11.5415603f           // 8 * log2(e) (T13 threshold in log2 domain)

DEVI short f2bf(float f) {
  unsigned u = __builtin_bit_cast(unsigned, f);
  u += 0x7FFFu + ((u >> 16) & 1u);
  return (short)(u >> 16);
}

DEVI unsigned cvtpk(float lo, float hi) {  // dword = [lo | hi<<16] as bf16 pair
  unsigned r;
  asm("v_cvt_pk_bf16_f32 %0, %1, %2" : "=v"(r) : "v"(lo), "v"(hi));
  return r;
}

DEVI float exp2a(float x) {  // v_exp_f32 = 2^x; s_nop covers trans-op hazard
  float r;
  asm volatile("v_exp_f32 %0, %1\n\ts_nop 1" : "=v"(r) : "v"(x));
  return r;
}

DEVI void gload16(const void* g, void* l) {
  __builtin_amdgcn_global_load_lds((const __attribute__((address_space(1))) unsigned*)g,
                                   (__attribute__((address_space(3))) unsigned*)l,
                                   16, 0, 0);
}

// ---------------- prep kernels ----------------

// state [B,H,L,D] f32 -> xbf [B,L,E] bf16
__global__ __launch_bounds__(256) void k_tr_state(const float* __restrict__ st,
                                                  short* __restrict__ xbf) {
  int idx = blockIdx.x * 256 + threadIdx.x;      // 8*12*2048*8 threads
  int dc = idx & 7;
  int l  = (idx >> 3) & 2047;
  int hb = idx >> 14;                            // b*12 + h
  int h = hb % 12, b = hb / 12;
  const float* s = st + ((size_t)hb * 2048 + l) * 64 + dc * 8;
  f4v a = *(const f4v*)s;
  f4v c = *(const f4v*)(s + 4);
  short o[8];
#pragma unroll
  for (int j = 0; j < 4; ++j) { o[j] = f2bf(a[j]); o[4 + j] = f2bf(c[j]); }
  *(s8v*)(xbf + ((size_t)(b * 2048 + l)) * 768 + h * 64 + dc * 8) = *(s8v*)o;
}

// Fused weight prep: 5 bf16 casts (Wk scaled into log2 domain) + bkv + zp-zero.
__global__ __launch_bounds__(256) void k_prep_w(
    const float* __restrict__ Wi, const float* __restrict__ Wk,
    const float* __restrict__ Wv, const float* __restrict__ Wao,
    const float* __restrict__ Wo, const float* __restrict__ bk,
    const float* __restrict__ bv, short* __restrict__ wib,
    short* __restrict__ wkb, short* __restrict__ wvb,
    short* __restrict__ waob, short* __restrict__ wob,
    float* __restrict__ bkv, short* __restrict__ zp) {
  const int bid = blockIdx.x;
  if (bid < 1440) {
    const int sel = bid / 288, off = bid % 288;
    const float* src;
    short* dst;
    float sc = 1.0f;
    switch (sel) {
      case 0: src = Wi;  dst = wib;  break;
      case 1: src = Wk;  dst = wkb;  sc = KSCALE; break;
      case 2: src = Wv;  dst = wvb;  break;
      case 3: src = Wao; dst = waob; break;
      default: src = Wo; dst = wob;  break;
    }
    const int idx = off * 256 + threadIdx.x;
    const float* s = src + (size_t)idx * 8;
    f4v a = *(const f4v*)s;
    f4v c = *(const f4v*)(s + 4);
    short o[8];
#pragma unroll
    for (int j = 0; j < 4; ++j) { o[j] = f2bf(a[j] * sc); o[4 + j] = f2bf(c[j] * sc); }
    *(s8v*)(dst + (size_t)idx * 8) = *(s8v*)o;
  } else if (bid < 1446) {
    const int i = (bid - 1440) * 256 + threadIdx.x;
    bkv[i] = (i < 768) ? bk[i] * KSCALE : bv[i - 768];
  } else {
    zp[threadIdx.x] = 0;
  }
}

// Wq [3][768][768] f32 -> Wqt [768][2304] bf16 : Wqt[o][kw*768+i] = Wq[kw][i][o]
__global__ __launch_bounds__(256) void k_tr_wq(const float* __restrict__ wq,
                                               short* __restrict__ wqt) {
  __shared__ float tile[32][33];
  const int kw = blockIdx.z;
  const int i0 = blockIdx.y * 32, o0 = blockIdx.x * 32;
  const int tx = threadIdx.x & 31, ty = threadIdx.x >> 5;
#pragma unroll
  for (int rr = 0; rr < 32; rr += 8)
    tile[ty + rr][tx] = wq[((size_t)kw * 768 + i0 + ty + rr) * 768 + o0 + tx];
  __syncthreads();
#pragma unroll
  for (int rr = 0; rr < 32; rr += 8)
    wqt[(size_t)(o0 + ty + rr) * 2304 + kw * 768 + i0 + tx] = f2bf(tile[tx][ty + rr]);
}

// v rows (stride `vs`) -> vt [96*64][2048] bf16 : vt[bh*64+d][l] = v[b][l][d]
__global__ __launch_bounds__(256) void k_tr_v(const short* __restrict__ v,
                                              short* __restrict__ vt, int vs) {
  __shared__ short tile[32][33];
  const int bh = blockIdx.z;
  const int l0 = blockIdx.x * 32, d0 = blockIdx.y * 32;
  const int b = bh / 12, h = bh % 12;
  const int tx = threadIdx.x & 31, ty = threadIdx.x >> 5;
#pragma unroll
  for (int rr = 0; rr < 32; rr += 8)
    tile[ty + rr][tx] = v[((size_t)(b * 2048 + l0 + ty + rr)) * vs + h * 64 + d0 + tx];
  __syncthreads();
#pragma unroll
  for (int rr = 0; rr < 32; rr += 8)
    vt[((size_t)(bh * 64 + d0 + ty + rr)) * 2048 + l0 + tx] = tile[tx][ty + rr];
}

// ---------------- GEMM:  C = act(A @ Bt^T + bias) ----------------
// A [M,K] bf16 row-major (AMODE 1: conv-gathered view of y), Bt [N,K] bf16.
// EPI: 0 relu->bf16, 1 bf16, 2 final fp32 + strided residual.
template <int AMODE, int EPI>
__global__ __launch_bounds__(256, 2)
void k_gemm(const short* __restrict__ A, const short* __restrict__ Bt,
            const float* __restrict__ bias, short* __restrict__ Cbf,
            float* __restrict__ Cf, const float* __restrict__ st,
            const short* __restrict__ zp, int M, int N, int K) {
  __shared__ __align__(16) short As[128 * 32];
  __shared__ __align__(16) short Bs[128 * 32];
  const int tid = threadIdx.x;
  const int w = tid >> 6, l = tid & 63;
  const int g = l >> 4, r = l & 15;

  // XCD-aware bijective remap (T1): grid linear id -> contiguous chunk per XCD.
  const int nwg = gridDim.x * gridDim.y;               // always % 8 == 0 here
  const int lin = blockIdx.y * gridDim.x + blockIdx.x;
  const int lin2 = (lin & 7) * (nwg >> 3) + (lin >> 3);
  const int m0 = (lin2 / gridDim.x) * 128, n0 = (lin2 % gridDim.x) * 128;
  const int wm = w >> 1, wn = w & 1;

  f4v acc[4][4] = {};

  const int srow = 16 * w + (l >> 2);  // staging row within tile (+64 for issue 1)
  const int sc8 = 8 * (l & 3);         // staging col elem offset within BK=32

  const int nsteps = K >> 5;
  for (int ks = 0; ks < nsteps; ++ks) {
    const int kk = ks << 5;
    __syncthreads();  // all waves done reading LDS from previous step
    // ---- stage A ----
    if (AMODE == 0) {
      const short* a0 = A + ((size_t)(m0 + srow) * K + kk + sc8);
      gload16(a0, (char*)As + w * 1024);
      gload16(a0 + (size_t)64 * K, (char*)As + w * 1024 + 4096);
    } else {
      const int kw = ks / 24;                       // 768/32 = 24 steps per tap
      const int ii = (ks - kw * 24) * 32 + sc8;     // col within y
#pragma unroll
      for (int j = 0; j < 2; ++j) {
        int m = m0 + srow + 64 * j;
        int b = m >> 10, t = m & 1023;
        int lpos = 2 * t - 1 + kw;                  // in [-1, 2047]
        const short* a0 = (lpos < 0) ? (zp + sc8)
                                     : A + ((size_t)(b * 2048 + lpos) * 768 + ii);
        gload16(a0, (char*)As + w * 1024 + j * 4096);
      }
    }
    // ---- stage B ----
    {
      const short* b0 = Bt + ((size_t)(n0 + srow) * K + kk + sc8);
      gload16(b0, (char*)Bs + w * 1024);
      gload16(b0 + (size_t)64 * K, (char*)Bs + w * 1024 + 4096);
    }
    __syncthreads();  // compiler drains vmcnt(0) before barrier -> tiles ready
    // ---- compute ----
    s8v af[4], bfr[4];
#pragma unroll
    for (int mt = 0; mt < 4; ++mt)
      af[mt] = *(const s8v*)&As[(64 * wm + 16 * mt + r) * 32 + 8 * g];
#pragma unroll
    for (int nt = 0; nt < 4; ++nt)
      bfr[nt] = *(const s8v*)&Bs[(64 * wn + 16 * nt + r) * 32 + 8 * g];
#pragma unroll
    for (int mt = 0; mt < 4; ++mt)
#pragma unroll
      for (int nt = 0; nt < 4; ++nt)
        acc[mt][nt] = __builtin_amdgcn_mfma_f32_16x16x32_bf16(af[mt], bfr[nt],
                                                              acc[mt][nt], 0, 0, 0);
  }
  // ---- epilogue ----
#pragma unroll
  for (int nt = 0; nt < 4; ++nt) {
    const int col = n0 + 64 * wn + 16 * nt + r;
    const float bv = bias[col];
#pragma unroll
    for (int mt = 0; mt < 4; ++mt) {
#pragma unroll
      for (int i = 0; i < 4; ++i) {
        int row = m0 + 64 * wm + 16 * mt + 4 * g + i;
        float v = acc[mt][nt][i] + bv;
        if (EPI == 0) v = fmaxf(v, 0.f);
        if (EPI <= 1) {
          Cbf[(size_t)row * N + col] = f2bf(v);
        } else {
          int b = row >> 10, t = row & 1023;
          int h = col >> 6, dd = col & 63;
          float res = st[(((size_t)(b * 12 + h) * 2048) + 2 * t) * 64 + dd];
          Cf[(((size_t)(b * 12 + h) * 1024) + t) * 64 + dd] = v + res;
        }
      }
    }
  }
}

// ---------------- flash attention ----------------
// grid: B*H*16 blocks; block = (b,h, 64 q-rows); wave w owns q rows 16w..16w+15.
// Lane (g,r) owns q-row = qblk*64+16w+r. K pre-scaled by 0.125*log2e (exp2 domain).
//   QK^T: sacc[nt] = mfma(K_frag, Q_frag) -> sacc[nt][i] = S[j=16nt+4g+i][q=r]
//   PV  : oacc[mt] = mfma(Vt_frag, P_frag) -> oacc[mt][i] = O[d=16mt+4g+i][q=r]
// lrun kept as per-lane partial (linear recurrence, uniform alpha) -> cross-g
// reduced ONCE after the loop. Cross-g max shuffles only on non-defer tiles.
// K double-buffered; V single-buffered (staged at tile-top, consumed after the
// mid-tile vmcnt(0); WAR covered by end-of-tile barrier). LDS = 32 KB -> 5 blk/CU.
__global__ __launch_bounds__(256, 5)
void k_attn(const short* __restrict__ qb, const short* __restrict__ kvb,
            const short* __restrict__ vt, short* __restrict__ ob) {
  __shared__ __align__(16) short Ks[2][64 * 64];  // [j][d], xor-swizzled 128B rows
  __shared__ __align__(16) short Vts[64 * 64];    // [d][j], swizzled, single buf
  __shared__ __align__(16) short Ps[4][16 * 64];  // rotated chunks, stride 64

  // XCD remap: 16 consecutive blocks share (b,h) -> keep them on one XCD.
  const int lin = blockIdx.x;
  const int blk = (lin & 7) * 192 + (lin >> 3);
  const int qblk = blk & 15, bh = blk >> 4;
  const int b = bh / 12, h = bh % 12;
  const int tid = threadIdx.x;
  const int w = tid >> 6, l = tid & 63;
  const int g = l >> 4, r = l & 15;
  const int row = tid >> 3, p = tid & 7;  // staging: 32 rows/issue, 8x16B chunks/row

  // Q B-fragments straight from global (once per block; no LDS round-trip).
  const short* qrow = qb + ((size_t)(b * 1024 + qblk * 64 + 16 * w + r)) * 768 + h * 64;
  s8v qf[2];
  qf[0] = *(const s8v*)(qrow + 8 * g);
  qf[1] = *(const s8v*)(qrow + 32 + 8 * g);

  // Precomputed Ps write/read addresses (loop-invariant; chunk = +r rotation).
  unsigned* pswr[8];
#pragma unroll
  for (int k = 0; k < 8; ++k) {
    const int nt = k >> 1, t = k & 1;
    pswr[k] = (unsigned*)&Ps[w][r * 64 + 8 * ((2 * nt + (g >> 1) + r) & 7) +
                               4 * (g & 1) + 2 * t];
  }
  const s8v* psrd[2];
#pragma unroll
  for (int kc = 0; kc < 2; ++kc)
    psrd[kc] = (const s8v*)&Ps[w][r * 64 + 8 * ((4 * kc + g + r) & 7)];

  auto STAGEK = [&](int buf, int jb) {
#pragma unroll
    for (int iss = 0; iss < 2; ++iss) {
      int jr = row + 32 * iss;
      int c = p ^ (jr & 7);
      gload16(kvb + ((size_t)(b * 2048 + jb * 64 + jr)) * 1536 + h * 64 + 8 * c,
              (char*)Ks[buf] + iss * 4096 + w * 1024);
    }
  };
  auto STAGEV = [&](int jb) {
#pragma unroll
    for (int iss = 0; iss < 2; ++iss) {
      int jr = row + 32 * iss;
      int c = p ^ (jr & 7);
      gload16(vt + ((size_t)(bh * 64 + jr)) * 2048 + jb * 64 + 8 * c,
              (char*)Vts + iss * 4096 + w * 1024);
    }
  };

  f4v oacc[4] = {};
  float mrun = -3.0e38f, lrun = 0.f;

  STAGEK(0, 0);
  asm volatile("s_waitcnt vmcnt(0)" ::: "memory");
  __builtin_amdgcn_s_barrier();

  for (int jb = 0; jb < 32; ++jb) {
    const int cur = jb & 1;
    STAGEV(jb);                             // V(jb): WAR safe (prev barrier)
    if (jb < 31) STAGEK(cur ^ 1, jb + 1);   // K(jb+1) prefetch

    // S^T = K Q^T  (K carries 0.125*log2e; scores in log2 domain)
    f4v sacc[4] = {};
    __builtin_amdgcn_s_setprio(1);
#pragma unroll
    for (int nt = 0; nt < 4; ++nt)
#pragma unroll
      for (int c = 0; c < 2; ++c) {
        s8v kf = *(const s8v*)&Ks[cur][(16 * nt + r) * 64 + 8 * ((4 * c + g) ^ (r & 7))];
        sacc[nt] = __builtin_amdgcn_mfma_f32_16x16x32_bf16(kf, qf[c], sacc[nt], 0, 0, 0);
      }
    __builtin_amdgcn_s_setprio(0);

    // lane-local online softmax for q=r (16 j's/lane); cross-g only when needed
    float s[16];
#pragma unroll
    for (int nt = 0; nt < 4; ++nt)
#pragma unroll
      for (int i = 0; i < 4; ++i) s[4 * nt + i] = sacc[nt][i];
    float m0 = fmaxf(fmaxf(s[0], s[1]), s[2]);
    float m1 = fmaxf(fmaxf(s[3], s[4]), s[5]);
    float m2 = fmaxf(fmaxf(s[6], s[7]), s[8]);
    float m3 = fmaxf(fmaxf(s[9], s[10]), s[11]);
    float m4 = fmaxf(fmaxf(s[12], s[13]), s[14]);
    float mloc = fmaxf(fmaxf(fmaxf(m0, m1), fmaxf(m2, m3)), fmaxf(m4, s[15]));

    float mn = mrun;
    if (!__all(mloc <= mrun + DEFTHR)) {    // T13 defer: skip shuffles + rescale
      float mx = mloc;
      mx = fmaxf(mx, __shfl_xor(mx, 16));
      mx = fmaxf(mx, __shfl_xor(mx, 32));
      mn = fmaxf(mrun, mx);
      float alpha = exp2a(mrun - mn);
      mrun = mn;
#pragma unroll
      for (int mt = 0; mt < 4; ++mt)
#pragma unroll
        for (int i = 0; i < 4; ++i) oacc[mt][i] *= alpha;
      lrun *= alpha;
    }

    float ls = 0.f;
#pragma unroll
    for (int k = 0; k < 8; ++k) {
      float p0 = exp2a(s[2 * k] - mn);
      float p1 = exp2a(s[2 * k + 1] - mn);
      ls += p0 + p1;
      *pswr[k] = cvtpk(p0, p1);  // bf16 pair (T12 primitive)
    }
    lrun += ls;  // per-lane partial; cross-g reduced after the loop

    asm volatile("s_waitcnt vmcnt(0)" ::: "memory");  // V(jb) (and K(jb+1)) landed
    asm volatile("" ::: "memory");                    // order Ps writes before reads
    s8v pf0 = *psrd[0], pf1 = *psrd[1];
    // O^T = V^T P^T
    __builtin_amdgcn_s_setprio(1);
#pragma unroll
    for (int mt = 0; mt < 4; ++mt) {
      s8v vf0 = *(const s8v*)&Vts[(16 * mt + r) * 64 + 8 * ((g) ^ (r & 7))];
      s8v vf1 = *(const s8v*)&Vts[(16 * mt + r) * 64 + 8 * ((4 + g) ^ (r & 7))];
      oacc[mt] = __builtin_amdgcn_mfma_f32_16x16x32_bf16(vf0, pf0, oacc[mt], 0, 0, 0);
      oacc[mt] = __builtin_amdgcn_mfma_f32_16x16x32_bf16(vf1, pf1, oacc[mt], 0, 0, 0);
    }
    __builtin_amdgcn_s_setprio(0);

    __builtin_amdgcn_s_barrier();  // everyone done with Ks[cur] & Vts
  }

  lrun += __shfl_xor(lrun, 16);
  lrun += __shfl_xor(lrun, 32);
  const float inv = 1.f / lrun;
  short* obase = ob + ((size_t)(b * 1024 + qblk * 64 + 16 * w + r)) * 768 + h * 64;
#pragma unroll
  for (int mt = 0; mt < 4; ++mt) {
    uint2 uu;
    uu.x = cvtpk(oacc[mt][0] * inv, oacc[mt][1] * inv);
    uu.y = cvtpk(oacc[mt][2] * inv, oacc[mt][3] * inv);
    *(uint2*)(obase + 16 * mt + 4 * g) = uu;
  }
}

// ---------------- launch ----------------
extern "C" void kernel_launch(void* const* d_in, const int* in_sizes, int n_in,
                              void* d_out, int out_size, void* d_ws, size_t ws_size,
                              hipStream_t stream) {
  const float* state = (const float*)d_in[0];
  const float* Wi  = (const float*)d_in[1];
  const float* bi  = (const float*)d_in[2];
  const float* Wq  = (const float*)d_in[3];
  const float* bq  = (const float*)d_in[4];
  const float* Wk  = (const float*)d_in[5];
  const float* bk  = (const float*)d_in[6];
  const float* Wv  = (const float*)d_in[7];
  const float* bv  = (const float*)d_in[8];
  const float* Wao = (const float*)d_in[9];
  const float* bao = (const float*)d_in[10];
  const float* Wo  = (const float*)d_in[11];
  const float* bo  = (const float*)d_in[12];
  float* out = (float*)d_out;

  char* ws = (char*)d_ws;
  const size_t SZ = (size_t)16384 * 768 * 2;  // 25165824 B
  short* xbf = (short*)ws;                    // [B,L,E] bf16; reused later as vt
  short* y   = (short*)(ws + SZ);             // [B,L,E]; reused as attno/z1
  short* kvbf = (short*)(ws + 2 * SZ);        // fused [16384][1536]: K|V
  short* qbf = (short*)(ws + 4 * SZ);         // [B,Lq,E] = SZ/2
  char*  wp  = ws + 4 * SZ + SZ / 2;
  short* wib  = (short*)wp;
  short* wkb  = (short*)(wp + 1 * 1179648);   // wkb|wvb contiguous = fused Bt
  short* wvb  = (short*)(wp + 2 * 1179648);
  short* waob = (short*)(wp + 3 * 1179648);
  short* wob  = (short*)(wp + 4 * 1179648);
  short* wqt  = (short*)(wp + 5 * 1179648);
  short* zp   = (short*)(wp + 5 * 1179648 + 3538944);
  float* bkv  = (float*)(wp + 5 * 1179648 + 3538944 + 512);
  short* vtb   = xbf;                // valid: xbf dead after GEMM1
  short* attno = y;                  // valid: y dead after q/kv GEMMs
  short* z1    = (short*)((char*)y + SZ / 2);

  k_tr_state<<<6144, 256, 0, stream>>>(state, xbf);
  k_prep_w<<<1447, 256, 0, stream>>>(Wi, Wk, Wv, Wao, Wo, bk, bv,
                                     wib, wkb, wvb, waob, wob, bkv, zp);
  k_tr_wq<<<dim3(24, 24, 3), 256, 0, stream>>>(Wq, wqt);

  // y = relu(x @ Wi^T + bi)
  k_gemm<0, 0><<<dim3(6, 128), 256, 0, stream>>>(xbf, wib, bi, y, nullptr, nullptr, zp, 16384, 768, 768);
  // fused k|v = y @ [Wk*KSCALE; Wv]^T + [bk*KSCALE; bv]
  k_gemm<0, 1><<<dim3(12, 128), 256, 0, stream>>>(y, wkb, bkv, kvbf, nullptr, nullptr, zp, 16384, 1536, 768);
  // q = conv1d(y, Wq, stride 2, pad 1) + bq  (gathered GEMM, K = 2304)
  k_gemm<1, 1><<<dim3(6, 64), 256, 0, stream>>>(y, wqt, bq, qbf, nullptr, nullptr, zp, 8192, 768, 2304);
  // v transpose for PV fragment reads (reads V half of kvbf)
  k_tr_v<<<dim3(64, 2, 96), 256, 0, stream>>>(kvbf + 768, vtb, 1536);
  // flash attention
  k_attn<<<1536, 256, 0, stream>>>(qbf, kvbf, vtb, attno);
  // z1 = relu(attno @ Wao^T + bao)
  k_gemm<0, 0><<<dim3(6, 64), 256, 0, stream>>>(attno, waob, bao, z1, nullptr, nullptr, zp, 8192, 768, 768);
  // out = z1 @ Wo^T + bo + residual, reshaped to [B,H,Lq,D]
  k_gemm<0, 2><<<dim3(6, 64), 256, 0, stream>>>(z1, wob, bo, nullptr, out, state, zp, 8192, 768, 768);
}